// Round 12
// baseline (904.621 us; speedup 1.0000x reference)
//
#include <hip/hip_runtime.h>
#include <hip/hip_bf16.h>
#include <hip/hip_cooperative_groups.h>

namespace cg = cooperative_groups;

#define N_NODES 8192
#define HID 64

typedef __attribute__((ext_vector_type(8))) short bf16x8;
typedef __attribute__((ext_vector_type(4))) float f32x4;

// ---------------- whole GNN pipeline as ONE cooperative kernel -------------
// P0: deg=0 ; A = x @ W1 (unscaled)          [grid-stride]
// P1: deg_count (atomic per edge)            [grid-stride]
// P2: block 0: exclusive scan -> off/cursor; deg -> dinv=rsqrt(deg+1) in place
// P3: csr fill (bucketed by dst)             [grid-stride]
// P4: h1 = relu(dinv*(sum dinv[s]*A[s] + dinv*A)+b1); B = dinv .* (h1@W2)
// P5: h2 = relu(dinv*gather(B)+b2) -> bf16
// All loops grid-stride so ANY grid size is correct (launch computes the
// co-resident max from the occupancy API; grid.sync needs co-residency).
__global__ void __launch_bounds__(256, 4) k_gnn(
    const float* __restrict__ x, const int* __restrict__ src,
    const int* __restrict__ dst, const float* __restrict__ W1,
    const float* __restrict__ b1, const float* __restrict__ W2,
    const float* __restrict__ b2, int* __restrict__ degdinv,
    int* __restrict__ off, int* __restrict__ cursor, int* __restrict__ csr,
    float* __restrict__ A, float* __restrict__ B,
    __hip_bfloat16* __restrict__ h2b, int E)
{
    cg::grid_group grid = cg::this_grid();
    const int tid  = threadIdx.x;
    const int lane = tid & 63;
    const int wv   = tid >> 6;
    const int gtid = blockIdx.x * 256 + tid;
    const int nthr = gridDim.x * 256;
    const int gw   = blockIdx.x * 4 + wv;   // global wave id
    const int nw   = gridDim.x * 4;

    // ---- P0: zero deg; gemm1 unscaled (one row per wave, lane = out col)
    for (int i = gtid; i < N_NODES; i += nthr) degdinv[i] = 0;
    for (int r = gw; r < N_NODES; r += nw) {
        const float* xr = x + (size_t)r * 128;
        float a = 0.f;
#pragma unroll 8
        for (int k = 0; k < 128; ++k) a += xr[k] * W1[k * 64 + lane];
        A[(size_t)r * 64 + lane] = a;
    }
    grid.sync();

    // ---- P1: degree count
    for (int e = gtid; e < E; e += nthr) atomicAdd(&degdinv[dst[e]], 1);
    grid.sync();

    // ---- P2: scan (block 0 only): off/cursor; dinv in place over deg
    if (blockIdx.x == 0) {
        __shared__ int s[256];
        int v[32];
        int sum = 0;
        const int base = tid * 32;
#pragma unroll
        for (int j = 0; j < 32; ++j) { v[j] = degdinv[base + j]; sum += v[j]; }
        s[tid] = sum;
        __syncthreads();
        for (int d = 1; d < 256; d <<= 1) {
            int xx = (tid >= d) ? s[tid - d] : 0;
            __syncthreads();
            s[tid] += xx;
            __syncthreads();
        }
        int ex = s[tid] - sum;  // exclusive prefix over 32-node chunks
#pragma unroll
        for (int j = 0; j < 32; ++j) {
            off[base + j] = ex;
            cursor[base + j] = ex;
            ex += v[j];
            ((float*)degdinv)[base + j] = rsqrtf((float)(v[j] + 1));  // +1: self loop
        }
    }
    grid.sync();
    const float* dinv = (const float*)degdinv;

    // ---- P3: csr fill
    for (int e = gtid; e < E; e += nthr) {
        int pos = atomicAdd(&cursor[dst[e]], 1);
        csr[pos] = src[e];
    }
    grid.sync();

    // ---- P4: layer-1 gather + bias/relu + fused gemm2 (one node per wave)
    for (int node = gw; node < N_NODES; node += nw) {
        const float di = dinv[node];
        float acc = A[(size_t)node * 64 + lane] * di;  // self term: di*A[d]
        int k = off[node];
        const int end = (node == N_NODES - 1) ? E : off[node + 1];
        for (; k + 1 < end; k += 2) {
            int s0 = csr[k], s1 = csr[k + 1];
            float h0 = A[(size_t)s0 * 64 + lane] * dinv[s0];
            float h1 = A[(size_t)s1 * 64 + lane] * dinv[s1];
            acc += h0;
            acc += h1;
        }
        if (k < end) { int s0 = csr[k]; acc += A[(size_t)s0 * 64 + lane] * dinv[s0]; }
        float h1v = di * acc + b1[lane];
        h1v = h1v > 0.f ? h1v : 0.f;
        // fused gemm2 row: o[lane] = sum_kk h1[kk] * W2[kk][lane]
        float o = 0.f;
#pragma unroll 8
        for (int kk = 0; kk < HID; ++kk)
            o += __shfl(h1v, kk, 64) * W2[kk * 64 + lane];
        B[(size_t)node * 64 + lane] = o * di;   // pre-scaled Hs2
    }
    grid.sync();

    // ---- P5: layer-2 gather + bias/relu -> bf16
    for (int node = gw; node < N_NODES; node += nw) {
        float acc = B[(size_t)node * 64 + lane];
        int k = off[node];
        const int end = (node == N_NODES - 1) ? E : off[node + 1];
        for (; k + 1 < end; k += 2) {
            int s0 = csr[k], s1 = csr[k + 1];
            acc += B[(size_t)s0 * 64 + lane];
            acc += B[(size_t)s1 * 64 + lane];
        }
        if (k < end) acc += B[(size_t)csr[k] * 64 + lane];
        float v = dinv[node] * acc + b2[lane];
        v = v > 0.f ? v : 0.f;
        h2b[(size_t)node * 64 + lane] = __float2bfloat16(v);
    }
}

// ---------------- sim = sigmoid(h @ h^T), bf16 MFMA ----------------
// block = 256 thr (4 waves), block tile 128x128, wave tile 64x64 (4x4 MFMA
// tiles). LDS-staged f32x4 stores (measured neutral vs raw stores in R8/R10
// A/B -- both at the ~43us write floor; kept).
__global__ void __launch_bounds__(256) k_sim(const short* __restrict__ Hb,
                                             float* __restrict__ out) {
    __shared__ float lds[64][132];
    const int lane = threadIdx.x & 63;
    const int wv   = threadIdx.x >> 6;
    const int rh   = wv >> 1;
    const int ch   = wv & 1;
    const int br = blockIdx.y * 128 + rh * 64;
    const int bc = blockIdx.x * 128 + ch * 64;
    const int lr = lane & 15;
    const int kg = lane >> 4;

    bf16x8 a[4][2], b[4][2];
#pragma unroll
    for (int t = 0; t < 4; ++t)
#pragma unroll
        for (int kk = 0; kk < 2; ++kk) {
            a[t][kk] = *(const bf16x8*)(Hb + (size_t)(br + t * 16 + lr) * 64 + kk * 32 + kg * 8);
            b[t][kk] = *(const bf16x8*)(Hb + (size_t)(bc + t * 16 + lr) * 64 + kk * 32 + kg * 8);
        }

    f32x4 acc[4][4] = {};
#pragma unroll
    for (int i = 0; i < 4; ++i)
#pragma unroll
        for (int j = 0; j < 4; ++j) {
            acc[i][j] = __builtin_amdgcn_mfma_f32_16x16x32_bf16(a[i][0], b[j][0], acc[i][j], 0, 0, 0);
            acc[i][j] = __builtin_amdgcn_mfma_f32_16x16x32_bf16(a[i][1], b[j][1], acc[i][j], 0, 0, 0);
        }

#pragma unroll
    for (int i = 0; i < 4; ++i)
#pragma unroll
        for (int j = 0; j < 4; ++j)
#pragma unroll
            for (int r = 0; r < 4; ++r)
                acc[i][j][r] = 1.0f / (1.0f + __expf(-acc[i][j][r]));

    const int orow = threadIdx.x >> 5;
    const int oq   = threadIdx.x & 31;
    const size_t ocol = (size_t)blockIdx.x * 128 + oq * 4;
#pragma unroll
    for (int h = 0; h < 2; ++h) {
        if (rh == h) {
#pragma unroll
            for (int i = 0; i < 4; ++i)
#pragma unroll
                for (int j = 0; j < 4; ++j)
#pragma unroll
                    for (int r = 0; r < 4; ++r)
                        lds[i * 16 + kg * 4 + r][ch * 64 + j * 16 + lr] = acc[i][j][r];
        }
        __syncthreads();
#pragma unroll
        for (int p = 0; p < 8; ++p) {
            int rr = p * 8 + orow;
            f32x4 v = *(const f32x4*)&lds[rr][oq * 4];
            *(f32x4*)&out[(size_t)(blockIdx.y * 128 + h * 64 + rr) * N_NODES + ocol] = v;
        }
        __syncthreads();
    }
}

extern "C" void kernel_launch(void* const* d_in, const int* in_sizes, int n_in,
                              void* d_out, int out_size, void* d_ws, size_t ws_size,
                              hipStream_t stream) {
    const float* x  = (const float*)d_in[0];
    const int*   ei = (const int*)d_in[1];
    const float* W1 = (const float*)d_in[2];
    const float* b1 = (const float*)d_in[3];
    const float* W2 = (const float*)d_in[4];
    const float* b2 = (const float*)d_in[5];
    int E = in_sizes[1] / 2;
    const int* src = ei;
    const int* dst = ei + E;

    // Workspace layout:
    //   degdinv : 0..32K        (int edge-deg -> float rsqrt(deg+1) in P2)
    //   off     : 32K..64K      (8192 ints exactly; off[8192] not stored)
    //   cursor  : 64K..96K      (own buffer: P0 writes A before P3 uses cursor)
    //   csr     : 96K..96K+1M
    //   A       : +2MB          (unscaled x@W1; h2b bf16 aliases A after P4)
    //   B       : +2MB          (Hs2)
    char* ws = (char*)d_ws;
    int*   degdinv = (int*)ws;
    int*   off     = (int*)(ws + 32 * 1024);
    int*   cursor  = (int*)(ws + 64 * 1024);
    int*   csr     = (int*)(ws + 96 * 1024);
    float* A       = (float*)(ws + 96 * 1024 + 1024 * 1024);
    float* B       = (float*)(ws + 96 * 1024 + 3 * 1024 * 1024);
    __hip_bfloat16* h2b = (__hip_bfloat16*)A;  // A dead after P4

    // cooperative grid: co-resident max (grid-stride phases are size-agnostic)
    int mb = 0;
    hipOccupancyMaxActiveBlocksPerMultiprocessor(&mb, (const void*)k_gnn, 256, 0);
    if (mb < 1) mb = 1;
    int nb = mb * 256;               // 256 CUs on MI355X
    if (nb > 1024) nb = 1024;

    void* kargs[] = {(void*)&x, (void*)&src, (void*)&dst, (void*)&W1, (void*)&b1,
                     (void*)&W2, (void*)&b2, (void*)&degdinv, (void*)&off,
                     (void*)&cursor, (void*)&csr, (void*)&A, (void*)&B,
                     (void*)&h2b, (void*)&E};
    hipLaunchCooperativeKernel((const void*)k_gnn, dim3(nb), dim3(256), kargs, 0, stream);

    // sim = sigmoid(h2 @ h2^T)
    dim3 g(N_NODES / 128, N_NODES / 128);
    k_sim<<<g, 256, 0, stream>>>((const short*)h2b, (float*)d_out);
}

// Round 13
// 352.891 us; speedup vs baseline: 2.5635x; 2.5635x over previous
//
#include <hip/hip_runtime.h>
#include <hip/hip_bf16.h>

#define N_NODES 8192
#define HID 64

typedef __attribute__((ext_vector_type(8))) short bf16x8;
typedef __attribute__((ext_vector_type(4))) float f32x4;

// ---------------- degree count (deg buffer memset to 0 by host code) -------
__global__ void k_deg_count(const int* __restrict__ dst, int* __restrict__ deg, int E) {
    int e = blockIdx.x * 256 + threadIdx.x;
    if (e < E) atomicAdd(&deg[dst[e]], 1);
}

// ---------------- CSR offsets + dinv (fused) ------------------------------
// deg[i] = edge count (no self loop). Exclusive scan over 8192 nodes, one
// block. Also converts deg -> dinv = rsqrt(deg+1) in place (self loop +1).
// off has EXACTLY 8192 ints; off[8192] NOT stored (gather uses E for last
// node) -- storing it was the R7 crash.
__global__ void __launch_bounds__(1024) k_scan(int* __restrict__ degdinv,
                                               int* __restrict__ off,
                                               int* __restrict__ cursor) {
    __shared__ int s[1024];
    const int t = threadIdx.x;
    int v[8];
    int sum = 0;
    const int base = t * 8;
#pragma unroll
    for (int j = 0; j < 8; ++j) { v[j] = degdinv[base + j]; sum += v[j]; }
    s[t] = sum;
    __syncthreads();
    for (int d = 1; d < 1024; d <<= 1) {
        int x = (t >= d) ? s[t - d] : 0;
        __syncthreads();
        s[t] += x;
        __syncthreads();
    }
    int ex = s[t] - sum;  // exclusive prefix
#pragma unroll
    for (int j = 0; j < 8; ++j) {
        off[base + j] = ex;
        cursor[base + j] = ex;
        ex += v[j];
        ((float*)degdinv)[base + j] = rsqrtf((float)(v[j] + 1));  // dinv in place
    }
}

// ---------------- FUSED: csr fill (blocks 0..EB-1)  ||  gemm1 (rest) -------
// Independent work items sharing one dispatch: fill consumes cursor (from
// scan); gemm1 reads x/W1/dinv and writes A. cursor must NOT alias A.
// gemm1: Y[r] = dinv[r] * (X[8192,128] @ W1[128,64])[r]
__global__ void __launch_bounds__(256) k_fill_gemm1(
    const int* __restrict__ src, const int* __restrict__ dst,
    int* __restrict__ cursor, int* __restrict__ csr, int E, int EB,
    const float* __restrict__ X, const float* __restrict__ W1,
    const float* __restrict__ dinv, float* __restrict__ Y) {
    if ((int)blockIdx.x < EB) {
        int e = blockIdx.x * 256 + threadIdx.x;
        if (e >= E) return;
        int pos = atomicAdd(&cursor[dst[e]], 1);
        csr[pos] = src[e];
    } else {
        const int b    = blockIdx.x - EB;
        const int col  = threadIdx.x & 63;
        const int wv   = threadIdx.x >> 6;
        const int row0 = b * 16 + wv * 4;
        float a0 = 0.f, a1 = 0.f, a2 = 0.f, a3 = 0.f;
        const float* x0 = X + (size_t)row0 * 128;
        for (int k = 0; k < 128; ++k) {
            float w = W1[k * 64 + col];
            a0 += x0[k] * w;
            a1 += x0[128 + k] * w;
            a2 += x0[256 + k] * w;
            a3 += x0[384 + k] * w;
        }
        size_t o = (size_t)row0 * 64 + col;
        Y[o]       = a0 * dinv[row0];
        Y[o + 64]  = a1 * dinv[row0 + 1];
        Y[o + 128] = a2 * dinv[row0 + 2];
        Y[o + 192] = a3 * dinv[row0 + 3];
    }
}

// ---------------- layer-1 gather + bias/relu + FUSED gemm2 -----------------
// Per node (one wave): h1[lane] = relu(dinv*gathersum(Hs1)+b1) in registers;
// then the h1 @ W2 row via 64 __shfl broadcasts. Out pre-scaled by dinv.
__global__ void __launch_bounds__(256) k_gather_gemm2(const float* __restrict__ Hs1,
                                                      const float* __restrict__ dinv,
                                                      const int* __restrict__ off,
                                                      const int* __restrict__ csr,
                                                      const float* __restrict__ b1,
                                                      const float* __restrict__ W2,
                                                      float* __restrict__ Hs2,
                                                      int E) {
    const int node = blockIdx.x * 4 + (threadIdx.x >> 6);
    const int lane = threadIdx.x & 63;
    float acc = Hs1[(size_t)node * 64 + lane];  // self-loop term (pre-scaled)
    int k = off[node];
    const int end = (node == N_NODES - 1) ? E : off[node + 1];
    for (; k + 1 < end; k += 2) {
        int s0 = csr[k];
        int s1 = csr[k + 1];
        float h0 = Hs1[(size_t)s0 * 64 + lane];
        float h1 = Hs1[(size_t)s1 * 64 + lane];
        acc += h0;
        acc += h1;
    }
    if (k < end) acc += Hs1[(size_t)csr[k] * 64 + lane];
    const float di = dinv[node];
    float h1v = di * acc + b1[lane];
    h1v = h1v > 0.f ? h1v : 0.f;

    float o = 0.f;
#pragma unroll 8
    for (int kk = 0; kk < HID; ++kk)
        o += __shfl(h1v, kk, 64) * W2[kk * 64 + lane];
    Hs2[(size_t)node * 64 + lane] = o * di;
}

// ---------------- layer-2 gather + bias/relu -> bf16 -----------------------
__global__ void __launch_bounds__(256) k_gather2(const float* __restrict__ Hs,
                                                 const float* __restrict__ dinv,
                                                 const int* __restrict__ off,
                                                 const int* __restrict__ csr,
                                                 const float* __restrict__ bias,
                                                 __hip_bfloat16* __restrict__ outb,
                                                 int E) {
    const int node = blockIdx.x * 4 + (threadIdx.x >> 6);
    const int lane = threadIdx.x & 63;
    float acc = Hs[(size_t)node * 64 + lane];
    int k = off[node];
    const int end = (node == N_NODES - 1) ? E : off[node + 1];
    for (; k + 1 < end; k += 2) {
        int s0 = csr[k];
        int s1 = csr[k + 1];
        float h0 = Hs[(size_t)s0 * 64 + lane];
        float h1 = Hs[(size_t)s1 * 64 + lane];
        acc += h0;
        acc += h1;
    }
    if (k < end) acc += Hs[(size_t)csr[k] * 64 + lane];
    float v = dinv[node] * acc + bias[lane];
    v = v > 0.f ? v : 0.f;
    outb[(size_t)node * 64 + lane] = __float2bfloat16(v);
}

// ---------------- sim = sigmoid(h @ h^T), bf16 MFMA ----------------
// block = 256 thr (4 waves), block tile 128x128, wave tile 64x64 (4x4 MFMA
// tiles). LDS-staged f32x4 stores (measured neutral vs raw stores R8/R10 --
// both at the ~43us write floor; kept).
__global__ void __launch_bounds__(256) k_sim(const short* __restrict__ Hb,
                                             float* __restrict__ out) {
    __shared__ float lds[64][132];
    const int lane = threadIdx.x & 63;
    const int wv   = threadIdx.x >> 6;
    const int rh   = wv >> 1;
    const int ch   = wv & 1;
    const int br = blockIdx.y * 128 + rh * 64;
    const int bc = blockIdx.x * 128 + ch * 64;
    const int lr = lane & 15;
    const int kg = lane >> 4;

    bf16x8 a[4][2], b[4][2];
#pragma unroll
    for (int t = 0; t < 4; ++t)
#pragma unroll
        for (int kk = 0; kk < 2; ++kk) {
            a[t][kk] = *(const bf16x8*)(Hb + (size_t)(br + t * 16 + lr) * 64 + kk * 32 + kg * 8);
            b[t][kk] = *(const bf16x8*)(Hb + (size_t)(bc + t * 16 + lr) * 64 + kk * 32 + kg * 8);
        }

    f32x4 acc[4][4] = {};
#pragma unroll
    for (int i = 0; i < 4; ++i)
#pragma unroll
        for (int j = 0; j < 4; ++j) {
            acc[i][j] = __builtin_amdgcn_mfma_f32_16x16x32_bf16(a[i][0], b[j][0], acc[i][j], 0, 0, 0);
            acc[i][j] = __builtin_amdgcn_mfma_f32_16x16x32_bf16(a[i][1], b[j][1], acc[i][j], 0, 0, 0);
        }

#pragma unroll
    for (int i = 0; i < 4; ++i)
#pragma unroll
        for (int j = 0; j < 4; ++j)
#pragma unroll
            for (int r = 0; r < 4; ++r)
                acc[i][j][r] = 1.0f / (1.0f + __expf(-acc[i][j][r]));

    const int orow = threadIdx.x >> 5;
    const int oq   = threadIdx.x & 31;
    const size_t ocol = (size_t)blockIdx.x * 128 + oq * 4;
#pragma unroll
    for (int h = 0; h < 2; ++h) {
        if (rh == h) {
#pragma unroll
            for (int i = 0; i < 4; ++i)
#pragma unroll
                for (int j = 0; j < 4; ++j)
#pragma unroll
                    for (int r = 0; r < 4; ++r)
                        lds[i * 16 + kg * 4 + r][ch * 64 + j * 16 + lr] = acc[i][j][r];
        }
        __syncthreads();
#pragma unroll
        for (int p = 0; p < 8; ++p) {
            int rr = p * 8 + orow;
            f32x4 v = *(const f32x4*)&lds[rr][oq * 4];
            *(f32x4*)&out[(size_t)(blockIdx.y * 128 + h * 64 + rr) * N_NODES + ocol] = v;
        }
        __syncthreads();
    }
}

extern "C" void kernel_launch(void* const* d_in, const int* in_sizes, int n_in,
                              void* d_out, int out_size, void* d_ws, size_t ws_size,
                              hipStream_t stream) {
    const float* x  = (const float*)d_in[0];
    const int*   ei = (const int*)d_in[1];
    const float* W1 = (const float*)d_in[2];
    const float* b1 = (const float*)d_in[3];
    const float* W2 = (const float*)d_in[4];
    const float* b2 = (const float*)d_in[5];
    const int E = in_sizes[1] / 2;
    const int* src = ei;
    const int* dst = ei + E;

    // Workspace layout (cursor NOT aliased with A -- fill runs || gemm1):
    //   degdinv : 0..32K        (int edge-deg -> float rsqrt(deg+1) in k_scan)
    //   off     : 32K..64K      (8192 ints exactly)
    //   cursor  : 64K..96K
    //   csr     : 96K..96K+1M   (src per edge)
    //   A       : +2MB          (Hs1 pre-scaled; h2b bf16 aliases A after P4)
    //   B       : +2MB          (Hs2 pre-scaled)
    char* ws = (char*)d_ws;
    int*   degdinv = (int*)ws;
    float* dinv    = (float*)ws;
    int*   off     = (int*)(ws + 32 * 1024);
    int*   cursor  = (int*)(ws + 64 * 1024);
    int*   csr     = (int*)(ws + 96 * 1024);
    float* A       = (float*)(ws + 96 * 1024 + 1024 * 1024);
    float* B       = (float*)(ws + 96 * 1024 + 3 * 1024 * 1024);
    __hip_bfloat16* h2b = (__hip_bfloat16*)A;  // A (Hs1) dead after gather_gemm2

    const int EB = (E + 255) / 256; // 1024
    const int GB = N_NODES / 4;     // 2048 blocks for gathers

    // preprocessing
    hipMemsetAsync(degdinv, 0, N_NODES * sizeof(int), stream);
    k_deg_count<<<EB, 256, 0, stream>>>(dst, degdinv, E);
    k_scan<<<1, 1024, 0, stream>>>(degdinv, off, cursor);   // offsets + dinv

    // fused: csr fill (1024 blocks) || gemm1 (512 blocks)
    k_fill_gemm1<<<EB + N_NODES / 16, 256, 0, stream>>>(src, dst, cursor, csr, E, EB,
                                                        x, W1, dinv, A);

    // layer 1 gather + fused layer-2 linear; then layer 2 gather -> bf16
    k_gather_gemm2<<<GB, 256, 0, stream>>>(A, dinv, off, csr, b1, W2, B, E);
    k_gather2<<<GB, 256, 0, stream>>>(B, dinv, off, csr, b2, h2b, E);

    // sim = sigmoid(h2 @ h2^T)
    dim3 g(N_NODES / 128, N_NODES / 128);
    k_sim<<<g, 256, 0, stream>>>((const short*)h2b, (float*)d_out);
}